// Round 1
// baseline (728.722 us; speedup 1.0000x reference)
//
#include <hip/hip_runtime.h>
#include <cstdint>
#include <cstddef>

#define B_ 8
#define N_ 10000
#define C_ 64
#define DIM_ 256
#define E_ 160000
#define ROWS_ (B_ * N_)            // 80000
#define OUT_OFF_ ((size_t)B_ * N_ * C_)  // 5,120,000

__device__ __forceinline__ float swish_f(float v, float sp) {
    // v * sigmoid(v * sp) / 1.1
    float s = 1.0f / (1.0f + expf(-v * sp));
    return v * s * (1.0f / 1.1f);
}

// ---- graph preprocessing -------------------------------------------------

__global__ void k_deg(const int* __restrict__ dst, const float* __restrict__ ew,
                      float* __restrict__ deg, int* __restrict__ cnt) {
    int e = blockIdx.x * 256 + threadIdx.x;
    if (e < E_) {
        int d = dst[e];
        atomicAdd(&deg[d], ew[e]);
        atomicAdd(&cnt[d], 1);
    }
}

__global__ void k_dis(const float* __restrict__ deg, float* __restrict__ dis) {
    int n = blockIdx.x * 256 + threadIdx.x;
    if (n < N_) {
        float d = deg[n];
        dis[n] = d > 0.f ? rsqrtf(d) : 0.f;
    }
}

__global__ void k_lapw(const int* __restrict__ src, const int* __restrict__ dst,
                       const float* __restrict__ ew, const float* __restrict__ dis,
                       float* __restrict__ lapw) {
    int e = blockIdx.x * 256 + threadIdx.x;
    if (e < E_) lapw[e] = -(dis[src[e]] * ew[e] * dis[dst[e]]);
}

// single-block exclusive scan of cnt[N] -> offs[N+1]; also seeds cursor
__global__ void k_scan(const int* __restrict__ cnt, int* __restrict__ offs,
                       int* __restrict__ cursor) {
    __shared__ int part[1024];
    int t = threadIdx.x;
    const int CH = 10;  // 1024*10 >= N_
    int base = t * CH;
    int s = 0;
    for (int i = 0; i < CH; i++) {
        int idx = base + i;
        if (idx < N_) s += cnt[idx];
    }
    part[t] = s;
    __syncthreads();
    for (int off = 1; off < 1024; off <<= 1) {
        int v = 0;
        if (t >= off) v = part[t - off];
        __syncthreads();
        if (t >= off) part[t] += v;
        __syncthreads();
    }
    int run = (t > 0) ? part[t - 1] : 0;
    for (int i = 0; i < CH; i++) {
        int idx = base + i;
        if (idx < N_) {
            offs[idx] = run;
            cursor[idx] = run;
            run += cnt[idx];
        }
    }
    if (t == 1023) offs[N_] = run;
}

__global__ void k_scatter(const int* __restrict__ src, const int* __restrict__ dst,
                          const float* __restrict__ lapw, int* __restrict__ cursor,
                          int* __restrict__ ssrc, float* __restrict__ sw) {
    int e = blockIdx.x * 256 + threadIdx.x;
    if (e < E_) {
        int p = atomicAdd(&cursor[dst[e]], 1);
        ssrc[p] = src[e];
        sw[p] = lapw[e];
    }
}

// gather propagation: O[b,n,c] = sum_{j in CSR(n)} T[b, ssrc[j], c] * sw[j]
__global__ void k_prop(const float* __restrict__ T, const int* __restrict__ offs,
                       const int* __restrict__ ssrc, const float* __restrict__ sw,
                       float* __restrict__ O) {
    int g = blockIdx.x * 256 + threadIdx.x;  // < B*N*C (divisible by 256)
    int c = g & 63;
    int bn = g >> 6;          // b*N + n
    int n = bn % N_;
    int b = g / (N_ * C_);
    const float* Tb = T + (size_t)b * N_ * C_;
    int s = offs[n], e = offs[n + 1];
    float sum = 0.f;
    for (int j = s; j < e; ++j) sum += Tb[ssrc[j] * C_ + c] * sw[j];
    O[g] = sum;
}

// ---- cheb einsum + swish: h[row, 0:256] ---------------------------------
// 16 rows per block, 256 threads, 4x4 register tile per thread.
__global__ __launch_bounds__(256) void k_cheb(
        const float* __restrict__ x, const float* __restrict__ Tx1,
        const float* __restrict__ P1, const float* __restrict__ Wc,
        const float* __restrict__ bc, const float* __restrict__ beta,
        float* __restrict__ h) {
    __shared__ float s0[1024], s1[1024], s2[1024];
    int t = threadIdx.x;
    size_t base = (size_t)blockIdx.x * 1024;  // 16 rows * 64
    for (int i = t; i < 1024; i += 256) {
        float a = x[base + i];
        s0[i] = a;
        s1[i] = Tx1[base + i];
        s2[i] = 2.f * P1[base + i] - a;
    }
    __syncthreads();
    float sp = logf(1.f + expf(beta[0]));
    int tx = t & 63, ty = t >> 6;
    int e0 = tx * 4;
    float acc[4][4] = {};
    for (int c = 0; c < 64; ++c) {
        float4 w0 = *(const float4*)&Wc[(0 * 64 + c) * 256 + e0];
        float4 w1 = *(const float4*)&Wc[(1 * 64 + c) * 256 + e0];
        float4 w2 = *(const float4*)&Wc[(2 * 64 + c) * 256 + e0];
#pragma unroll
        for (int r = 0; r < 4; ++r) {
            int row = ty * 4 + r;
            float a0 = s0[row * 64 + c];
            float a1 = s1[row * 64 + c];
            float a2 = s2[row * 64 + c];
            acc[r][0] += a0 * w0.x + a1 * w1.x + a2 * w2.x;
            acc[r][1] += a0 * w0.y + a1 * w1.y + a2 * w2.y;
            acc[r][2] += a0 * w0.z + a1 * w1.z + a2 * w2.z;
            acc[r][3] += a0 * w0.w + a1 * w1.w + a2 * w2.w;
        }
    }
    float4 bcv = *(const float4*)&bc[e0];
#pragma unroll
    for (int r = 0; r < 4; ++r) {
        size_t grow = (size_t)blockIdx.x * 16 + ty * 4 + r;
        float4 hv;
        hv.x = swish_f(acc[r][0] + bcv.x, sp);
        hv.y = swish_f(acc[r][1] + bcv.y, sp);
        hv.z = swish_f(acc[r][2] + bcv.z, sp);
        hv.w = swish_f(acc[r][3] + bcv.w, sp);
        *(float4*)&h[grow * 256 + e0] = hv;
    }
}

// ---- fused MLP: h -> swish(h@W1+b1) -> Fx = @W2+b2 -> outputs ------------
// 16 rows per block, 256 threads.
__global__ __launch_bounds__(256) void k_mlp(
        const float* __restrict__ h, const float* __restrict__ W1,
        const float* __restrict__ b1, const float* __restrict__ W2,
        const float* __restrict__ b2, const float* __restrict__ x,
        const float* __restrict__ beta, float* __restrict__ out) {
    __shared__ float sh[4096];   // h tile 16x256
    __shared__ float sh2[4096];  // swish(h@W1+b1) tile
    __shared__ float red[4096];  // 4 partial groups x 16 rows x 64 cols
    int t = threadIdx.x;
    size_t hbase = (size_t)blockIdx.x * 4096;
    {
        float4* sh4 = (float4*)sh;
        const float4* hg = (const float4*)(h + hbase);
        for (int i = t; i < 1024; i += 256) sh4[i] = hg[i];
    }
    __syncthreads();
    float sp = logf(1.f + expf(beta[0]));
    int tx = t & 63, ty = t >> 6;
    int e0 = tx * 4;
    {
        float acc[4][4] = {};
        for (int d = 0; d < 256; ++d) {
            float4 w = *(const float4*)&W1[d * 256 + e0];
#pragma unroll
            for (int r = 0; r < 4; ++r) {
                float a = sh[(ty * 4 + r) * 256 + d];
                acc[r][0] += a * w.x;
                acc[r][1] += a * w.y;
                acc[r][2] += a * w.z;
                acc[r][3] += a * w.w;
            }
        }
        float4 b1v = *(const float4*)&b1[e0];
        float4* sh24 = (float4*)sh2;
#pragma unroll
        for (int r = 0; r < 4; ++r) {
            float4 v;
            v.x = swish_f(acc[r][0] + b1v.x, sp);
            v.y = swish_f(acc[r][1] + b1v.y, sp);
            v.z = swish_f(acc[r][2] + b1v.z, sp);
            v.w = swish_f(acc[r][3] + b1v.w, sp);
            sh24[(ty * 4 + r) * 64 + tx] = v;
        }
    }
    __syncthreads();
    {
        int c = t & 63, g = t >> 6;
        float acc2[16] = {};
        for (int dd = 0; dd < 64; ++dd) {
            int d = g * 64 + dd;
            float w = W2[d * 64 + c];
#pragma unroll
            for (int r = 0; r < 16; ++r) acc2[r] += sh2[r * 256 + d] * w;
        }
#pragma unroll
        for (int r = 0; r < 16; ++r) red[g * 1024 + r * 64 + c] = acc2[r];
    }
    __syncthreads();
    {
        size_t rowbase = (size_t)blockIdx.x * 1024;  // 16 rows x 64 cols flat
#pragma unroll
        for (int k = 0; k < 4; ++k) {
            int idx = t + k * 256;
            float f = red[idx] + red[1024 + idx] + red[2048 + idx] + red[3072 + idx]
                    + b2[idx & 63];
            float xv = x[rowbase + idx];
            out[rowbase + idx] = f + xv;
            out[OUT_OFF_ + rowbase + idx] = f;
        }
    }
}

extern "C" void kernel_launch(void* const* d_in, const int* in_sizes, int n_in,
                              void* d_out, int out_size, void* d_ws, size_t ws_size,
                              hipStream_t stream) {
    const float* x    = (const float*)d_in[0];
    const float* ew   = (const float*)d_in[1];
    const float* Wc   = (const float*)d_in[2];
    const float* bc   = (const float*)d_in[3];
    const float* W1   = (const float*)d_in[4];
    const float* b1   = (const float*)d_in[5];
    const float* W2   = (const float*)d_in[6];
    const float* b2   = (const float*)d_in[7];
    const float* beta = (const float*)d_in[8];
    const int*   ei   = (const int*)d_in[9];
    const int* src = ei;
    const int* dst = ei + E_;
    float* out = (float*)d_out;

    // workspace layout (4-byte units, 16B-aligned blocks)
    float* ws = (float*)d_ws;
    float* deg    = ws + 0;         // N
    float* dis    = ws + 10000;     // N
    float* lapw   = ws + 20000;     // E
    int*   cnt    = (int*)(ws + 180000);   // N
    int*   offs   = (int*)(ws + 190000);   // N+1 (padded to 10008)
    int*   cursor = (int*)(ws + 200008);   // N
    int*   ssrc   = (int*)(ws + 210008);   // E
    float* sw     = ws + 370008;           // E
    float* Tx1    = ws + 530008;           // B*N*C = 5,120,000
    float* P1     = ws + 5650008;          // 5,120,000
    float* h      = ws + 10770008;         // B*N*DIM = 20,480,000
    // total = 31,250,008 floats = ~125 MB

    hipMemsetAsync(deg, 0, (size_t)N_ * sizeof(float), stream);
    hipMemsetAsync(cnt, 0, (size_t)N_ * sizeof(int), stream);

    k_deg<<<(E_ + 255) / 256, 256, 0, stream>>>(dst, ew, deg, cnt);
    k_dis<<<(N_ + 255) / 256, 256, 0, stream>>>(deg, dis);
    k_lapw<<<(E_ + 255) / 256, 256, 0, stream>>>(src, dst, ew, dis, lapw);
    k_scan<<<1, 1024, 0, stream>>>(cnt, offs, cursor);
    k_scatter<<<(E_ + 255) / 256, 256, 0, stream>>>(src, dst, lapw, cursor, ssrc, sw);
    k_prop<<<(B_ * N_ * C_) / 256, 256, 0, stream>>>(x, offs, ssrc, sw, Tx1);
    k_prop<<<(B_ * N_ * C_) / 256, 256, 0, stream>>>(Tx1, offs, ssrc, sw, P1);
    k_cheb<<<ROWS_ / 16, 256, 0, stream>>>(x, Tx1, P1, Wc, bc, beta, h);
    k_mlp<<<ROWS_ / 16, 256, 0, stream>>>(h, W1, b1, W2, b2, x, beta, out);
}

// Round 2
// 326.037 us; speedup vs baseline: 2.2351x; 2.2351x over previous
//
#include <hip/hip_runtime.h>
#include <cstdint>
#include <cstddef>

#define B_ 8
#define N_ 10000
#define C_ 64
#define DIM_ 256
#define E_ 160000
#define ROWS_ (B_ * N_)            // 80000
#define OUT_OFF_ ((size_t)B_ * N_ * C_)  // 5,120,000

typedef unsigned short u16;
typedef __attribute__((ext_vector_type(8))) short bf16x8;
typedef __attribute__((ext_vector_type(4))) float f32x4;

__device__ __forceinline__ u16 f2bf(float f) {
    unsigned int u = __float_as_uint(f);
    unsigned int r = u + 0x7FFF + ((u >> 16) & 1);  // RNE
    return (u16)(r >> 16);
}
__device__ __forceinline__ unsigned int pack2(float a, float b) {
    return (unsigned int)f2bf(a) | ((unsigned int)f2bf(b) << 16);
}
__device__ __forceinline__ float swish_f(float v, float sp) {
    float s = 1.0f / (1.0f + expf(-v * sp));
    return v * s * (1.0f / 1.1f);
}

// ---- graph preprocessing -------------------------------------------------

__global__ void k_deg(const int* __restrict__ dst, const float* __restrict__ ew,
                      float* __restrict__ deg, int* __restrict__ cnt) {
    int e = blockIdx.x * 256 + threadIdx.x;
    if (e < E_) {
        int d = dst[e];
        atomicAdd(&deg[d], ew[e]);
        atomicAdd(&cnt[d], 1);
    }
}

__global__ void k_dis(const float* __restrict__ deg, float* __restrict__ dis) {
    int n = blockIdx.x * 256 + threadIdx.x;
    if (n < N_) {
        float d = deg[n];
        dis[n] = d > 0.f ? rsqrtf(d) : 0.f;
    }
}

__global__ void k_lapw(const int* __restrict__ src, const int* __restrict__ dst,
                       const float* __restrict__ ew, const float* __restrict__ dis,
                       float* __restrict__ lapw) {
    int e = blockIdx.x * 256 + threadIdx.x;
    if (e < E_) lapw[e] = -(dis[src[e]] * ew[e] * dis[dst[e]]);
}

__global__ void k_scan(const int* __restrict__ cnt, int* __restrict__ offs,
                       int* __restrict__ cursor) {
    __shared__ int part[1024];
    int t = threadIdx.x;
    const int CH = 10;
    int base = t * CH;
    int s = 0;
    for (int i = 0; i < CH; i++) {
        int idx = base + i;
        if (idx < N_) s += cnt[idx];
    }
    part[t] = s;
    __syncthreads();
    for (int off = 1; off < 1024; off <<= 1) {
        int v = 0;
        if (t >= off) v = part[t - off];
        __syncthreads();
        if (t >= off) part[t] += v;
        __syncthreads();
    }
    int run = (t > 0) ? part[t - 1] : 0;
    for (int i = 0; i < CH; i++) {
        int idx = base + i;
        if (idx < N_) {
            offs[idx] = run;
            cursor[idx] = run;
            run += cnt[idx];
        }
    }
    if (t == 1023) offs[N_] = run;
}

__global__ void k_scatter(const int* __restrict__ src, const int* __restrict__ dst,
                          const float* __restrict__ lapw, int* __restrict__ cursor,
                          int* __restrict__ ssrc, float* __restrict__ sw) {
    int e = blockIdx.x * 256 + threadIdx.x;
    if (e < E_) {
        int p = atomicAdd(&cursor[dst[e]], 1);
        ssrc[p] = src[e];
        sw[p] = lapw[e];
    }
}

// gather propagation with 4x unroll for gather ILP
__global__ void k_prop(const float* __restrict__ T, const int* __restrict__ offs,
                       const int* __restrict__ ssrc, const float* __restrict__ sw,
                       float* __restrict__ O) {
    int g = blockIdx.x * 256 + threadIdx.x;
    int c = g & 63;
    int bn = g >> 6;
    int n = bn % N_;
    int b = g / (N_ * C_);
    const float* Tb = T + (size_t)b * N_ * C_;
    int s = offs[n], e = offs[n + 1];
    float sum = 0.f;
    int j = s;
    for (; j + 4 <= e; j += 4) {
        int i0 = ssrc[j], i1 = ssrc[j + 1], i2 = ssrc[j + 2], i3 = ssrc[j + 3];
        float w0 = sw[j], w1 = sw[j + 1], w2 = sw[j + 2], w3 = sw[j + 3];
        sum += Tb[i0 * C_ + c] * w0 + Tb[i1 * C_ + c] * w1
             + Tb[i2 * C_ + c] * w2 + Tb[i3 * C_ + c] * w3;
    }
    for (; j < e; ++j) sum += Tb[ssrc[j] * C_ + c] * sw[j];
    O[g] = sum;
}

// ---- weight prep: transpose to N-major bf16 ------------------------------
// Wct[n][t*64+c] = Wc[t][c][n]   (256 x 192)
// W1t[n][k]      = W1[k][n]      (256 x 256)
// W2t[n][k]      = W2[k][n]      (64 x 256)
__global__ void k_prepw(const float* __restrict__ Wc, const float* __restrict__ W1,
                        const float* __restrict__ W2, u16* __restrict__ Wct,
                        u16* __restrict__ W1t, u16* __restrict__ W2t) {
    int i = blockIdx.x * 256 + threadIdx.x;
    if (i < 49152) {
        int n = i / 192, k = i % 192;
        Wct[i] = f2bf(Wc[k * 256 + n]);  // Wc flat [t*64+c][256]
    } else if (i < 49152 + 65536) {
        int j = i - 49152;
        int n = j / 256, k = j % 256;
        W1t[j] = f2bf(W1[k * 256 + n]);
    } else if (i < 49152 + 65536 + 16384) {
        int j = i - 49152 - 65536;
        int n = j / 256, k = j % 256;
        W2t[j] = f2bf(W2[k * 64 + n]);
    }
}

// ---- fused cheb-einsum + MLP, bf16 MFMA ----------------------------------
// 32 rows/block, 256 threads (4 waves). A operands in LDS; B (weights) read
// directly from L2-resident transposed bf16 arrays.
__global__ __launch_bounds__(256) void k_fused(
        const float* __restrict__ x, const float* __restrict__ Tx1,
        const float* __restrict__ P1, const u16* __restrict__ Wct,
        const float* __restrict__ bc, const u16* __restrict__ W1t,
        const float* __restrict__ b1, const u16* __restrict__ W2t,
        const float* __restrict__ b2, const float* __restrict__ beta,
        float* __restrict__ out) {
    __shared__ u16 buf0[32 * 256];  // A0 (stride 192), later A2 (stride 256)
    __shared__ u16 buf1[32 * 256];  // A1 (stride 256)
    int t = threadIdx.x;

    // stage A0 = [x | Tx1 | 2*P1 - x] as bf16, row-major stride 192
    {
        size_t base4 = (size_t)blockIdx.x * 512;  // in float4 units
        const float4* x4 = (const float4*)x;
        const float4* t4 = (const float4*)Tx1;
        const float4* p4 = (const float4*)P1;
#pragma unroll
        for (int rep = 0; rep < 2; ++rep) {
            int p = t + rep * 256;
            int r = p >> 4, c4 = p & 15;
            float4 xv = x4[base4 + p];
            float4 tv = t4[base4 + p];
            float4 pv = p4[base4 + p];
            float4 t2;
            t2.x = 2.f * pv.x - xv.x; t2.y = 2.f * pv.y - xv.y;
            t2.z = 2.f * pv.z - xv.z; t2.w = 2.f * pv.w - xv.w;
            uint2 px = {pack2(xv.x, xv.y), pack2(xv.z, xv.w)};
            uint2 pt = {pack2(tv.x, tv.y), pack2(tv.z, tv.w)};
            uint2 p2 = {pack2(t2.x, t2.y), pack2(t2.z, t2.w)};
            *(uint2*)&buf0[r * 192 + c4 * 4] = px;
            *(uint2*)&buf0[r * 192 + 64 + c4 * 4] = pt;
            *(uint2*)&buf0[r * 192 + 128 + c4 * 4] = p2;
        }
    }
    __syncthreads();

    float sp = logf(1.f + expf(beta[0]));
    int lane = t & 63, w = t >> 6;
    int m = lane & 15, quad = lane >> 4;

    // ---- GEMM1: h = A0[32x192] @ Wc[192x256], +bc, swish -> buf1
    {
        f32x4 acc[2][4] = {};
        for (int kc = 0; kc < 6; ++kc) {
            int koff = kc * 32 + quad * 8;
            bf16x8 a0 = *(const bf16x8*)&buf0[m * 192 + koff];
            bf16x8 a1 = *(const bf16x8*)&buf0[(16 + m) * 192 + koff];
#pragma unroll
            for (int nt = 0; nt < 4; ++nt) {
                bf16x8 b = *(const bf16x8*)&Wct[(w * 64 + nt * 16 + m) * 192 + koff];
                acc[0][nt] = __builtin_amdgcn_mfma_f32_16x16x32_bf16(a0, b, acc[0][nt], 0, 0, 0);
                acc[1][nt] = __builtin_amdgcn_mfma_f32_16x16x32_bf16(a1, b, acc[1][nt], 0, 0, 0);
            }
        }
#pragma unroll
        for (int mt = 0; mt < 2; ++mt)
#pragma unroll
            for (int nt = 0; nt < 4; ++nt) {
                int col = w * 64 + nt * 16 + m;
                float bcv = bc[col];
#pragma unroll
                for (int i = 0; i < 4; ++i) {
                    int row = mt * 16 + quad * 4 + i;
                    buf1[row * 256 + col] = f2bf(swish_f(acc[mt][nt][i] + bcv, sp));
                }
            }
    }
    __syncthreads();

    // ---- GEMM2: h2 = A1[32x256] @ W1[256x256], +b1, swish -> buf0
    {
        f32x4 acc[2][4] = {};
        for (int kc = 0; kc < 8; ++kc) {
            int koff = kc * 32 + quad * 8;
            bf16x8 a0 = *(const bf16x8*)&buf1[m * 256 + koff];
            bf16x8 a1 = *(const bf16x8*)&buf1[(16 + m) * 256 + koff];
#pragma unroll
            for (int nt = 0; nt < 4; ++nt) {
                bf16x8 b = *(const bf16x8*)&W1t[(w * 64 + nt * 16 + m) * 256 + koff];
                acc[0][nt] = __builtin_amdgcn_mfma_f32_16x16x32_bf16(a0, b, acc[0][nt], 0, 0, 0);
                acc[1][nt] = __builtin_amdgcn_mfma_f32_16x16x32_bf16(a1, b, acc[1][nt], 0, 0, 0);
            }
        }
#pragma unroll
        for (int mt = 0; mt < 2; ++mt)
#pragma unroll
            for (int nt = 0; nt < 4; ++nt) {
                int col = w * 64 + nt * 16 + m;
                float b1v = b1[col];
#pragma unroll
                for (int i = 0; i < 4; ++i) {
                    int row = mt * 16 + quad * 4 + i;
                    buf0[row * 256 + col] = f2bf(swish_f(acc[mt][nt][i] + b1v, sp));
                }
            }
    }
    __syncthreads();

    // ---- GEMM3: Fx = A2[32x256] @ W2[256x64], +b2; out = Fx + x, Fx
    {
        f32x4 acc3[2] = {};
        for (int kc = 0; kc < 8; ++kc) {
            int koff = kc * 32 + quad * 8;
            bf16x8 a0 = *(const bf16x8*)&buf0[m * 256 + koff];
            bf16x8 a1 = *(const bf16x8*)&buf0[(16 + m) * 256 + koff];
            bf16x8 b = *(const bf16x8*)&W2t[(w * 16 + m) * 256 + koff];
            acc3[0] = __builtin_amdgcn_mfma_f32_16x16x32_bf16(a0, b, acc3[0], 0, 0, 0);
            acc3[1] = __builtin_amdgcn_mfma_f32_16x16x32_bf16(a1, b, acc3[1], 0, 0, 0);
        }
        int col = w * 16 + m;
        float b2v = b2[col];
#pragma unroll
        for (int mt = 0; mt < 2; ++mt)
#pragma unroll
            for (int i = 0; i < 4; ++i) {
                int row = mt * 16 + quad * 4 + i;
                size_t g = ((size_t)blockIdx.x * 32 + row) * 64 + col;
                float f = acc3[mt][i] + b2v;
                out[g] = f + x[g];
                out[OUT_OFF_ + g] = f;
            }
    }
}

extern "C" void kernel_launch(void* const* d_in, const int* in_sizes, int n_in,
                              void* d_out, int out_size, void* d_ws, size_t ws_size,
                              hipStream_t stream) {
    const float* x    = (const float*)d_in[0];
    const float* ew   = (const float*)d_in[1];
    const float* Wc   = (const float*)d_in[2];
    const float* bc   = (const float*)d_in[3];
    const float* W1   = (const float*)d_in[4];
    const float* b1   = (const float*)d_in[5];
    const float* W2   = (const float*)d_in[6];
    const float* b2   = (const float*)d_in[7];
    const float* beta = (const float*)d_in[8];
    const int*   ei   = (const int*)d_in[9];
    const int* src = ei;
    const int* dst = ei + E_;
    float* out = (float*)d_out;

    // workspace layout (float units)
    float* ws = (float*)d_ws;
    float* deg    = ws + 0;                // N
    float* dis    = ws + 10000;            // N
    float* lapw   = ws + 20000;            // E
    int*   cnt    = (int*)(ws + 180000);   // N
    int*   offs   = (int*)(ws + 190000);   // N+1
    int*   cursor = (int*)(ws + 200008);   // N
    int*   ssrc   = (int*)(ws + 210008);   // E
    float* sw     = ws + 370008;           // E
    float* Tx1    = ws + 530008;           // B*N*C
    float* P1     = ws + 5650008;          // B*N*C
    u16*   Wct    = (u16*)(ws + 10770008); // 49152 bf16
    u16*   W1t    = (u16*)(ws + 10794584); // 65536 bf16
    u16*   W2t    = (u16*)(ws + 10827352); // 16384 bf16
    // total ~10.84M floats (~43 MB)

    hipMemsetAsync(deg, 0, (size_t)N_ * sizeof(float), stream);
    hipMemsetAsync(cnt, 0, (size_t)N_ * sizeof(int), stream);

    k_deg<<<(E_ + 255) / 256, 256, 0, stream>>>(dst, ew, deg, cnt);
    k_dis<<<(N_ + 255) / 256, 256, 0, stream>>>(deg, dis);
    k_lapw<<<(E_ + 255) / 256, 256, 0, stream>>>(src, dst, ew, dis, lapw);
    k_scan<<<1, 1024, 0, stream>>>(cnt, offs, cursor);
    k_scatter<<<(E_ + 255) / 256, 256, 0, stream>>>(src, dst, lapw, cursor, ssrc, sw);
    k_prepw<<<(131072 + 255) / 256, 256, 0, stream>>>(Wc, W1, W2, Wct, W1t, W2t);
    k_prop<<<(B_ * N_ * C_) / 256, 256, 0, stream>>>(x, offs, ssrc, sw, Tx1);
    k_prop<<<(B_ * N_ * C_) / 256, 256, 0, stream>>>(Tx1, offs, ssrc, sw, P1);
    k_fused<<<ROWS_ / 32, 256, 0, stream>>>(x, Tx1, P1, Wct, bc, W1t, b1, W2t, b2, beta, out);
}

// Round 3
// 320.662 us; speedup vs baseline: 2.2726x; 1.0168x over previous
//
#include <hip/hip_runtime.h>
#include <cstdint>
#include <cstddef>

#define B_ 8
#define N_ 10000
#define C_ 64
#define DIM_ 256
#define E_ 160000
#define ROWS_ (B_ * N_)            // 80000
#define OUT_OFF_ ((size_t)B_ * N_ * C_)  // 5,120,000

typedef unsigned short u16;
typedef unsigned int u32;
typedef __attribute__((ext_vector_type(8))) short bf16x8;
typedef __attribute__((ext_vector_type(4))) float f32x4;

__device__ __forceinline__ u16 f2bf(float f) {
    unsigned int u = __float_as_uint(f);
    unsigned int r = u + 0x7FFF + ((u >> 16) & 1);  // RNE
    return (u16)(r >> 16);
}
__device__ __forceinline__ float bf2f(u32 h) {      // low 16 bits hold bf16
    return __uint_as_float(h << 16);
}
__device__ __forceinline__ unsigned int pack2(float a, float b) {
    return (unsigned int)f2bf(a) | ((unsigned int)f2bf(b) << 16);
}
__device__ __forceinline__ float swish_f(float v, float sp) {
    float e = __expf(-v * sp);
    float s = __builtin_amdgcn_rcpf(1.0f + e);
    return v * s * (1.0f / 1.1f);
}

// ---- graph preprocessing -------------------------------------------------

__global__ void k_deg(const int* __restrict__ dst, const float* __restrict__ ew,
                      float* __restrict__ deg, int* __restrict__ cnt) {
    int e = blockIdx.x * 256 + threadIdx.x;
    if (e < E_) {
        int d = dst[e];
        atomicAdd(&deg[d], ew[e]);
        atomicAdd(&cnt[d], 1);
    }
}

__global__ void k_dis(const float* __restrict__ deg, float* __restrict__ dis) {
    int n = blockIdx.x * 256 + threadIdx.x;
    if (n < N_) {
        float d = deg[n];
        dis[n] = d > 0.f ? rsqrtf(d) : 0.f;
    }
}

__global__ void k_scan(const int* __restrict__ cnt, int* __restrict__ offs,
                       int* __restrict__ cursor) {
    __shared__ int part[1024];
    int t = threadIdx.x;
    const int CH = 10;
    int base = t * CH;
    int s = 0;
    for (int i = 0; i < CH; i++) {
        int idx = base + i;
        if (idx < N_) s += cnt[idx];
    }
    part[t] = s;
    __syncthreads();
    for (int off = 1; off < 1024; off <<= 1) {
        int v = 0;
        if (t >= off) v = part[t - off];
        __syncthreads();
        if (t >= off) part[t] += v;
        __syncthreads();
    }
    int run = (t > 0) ? part[t - 1] : 0;
    for (int i = 0; i < CH; i++) {
        int idx = base + i;
        if (idx < N_) {
            offs[idx] = run;
            cursor[idx] = run;
            run += cnt[idx];
        }
    }
    if (t == 1023) offs[N_] = run;
}

// scatter with inline lapw computation
__global__ void k_scatter(const int* __restrict__ src, const int* __restrict__ dst,
                          const float* __restrict__ ew, const float* __restrict__ dis,
                          int* __restrict__ cursor, int* __restrict__ ssrc,
                          float* __restrict__ sw) {
    int e = blockIdx.x * 256 + threadIdx.x;
    if (e < E_) {
        int sn = src[e], dn = dst[e];
        float w = -(dis[sn] * ew[e] * dis[dn]);
        int p = atomicAdd(&cursor[dn], 1);
        ssrc[p] = sn;
        sw[p] = w;
    }
}

// weight transpose to N-major bf16 + x cast to bf16
__global__ void k_prepw(const float* __restrict__ Wc, const float* __restrict__ W1,
                        const float* __restrict__ W2, const float* __restrict__ x,
                        u16* __restrict__ Wct, u16* __restrict__ W1t,
                        u16* __restrict__ W2t, u16* __restrict__ xbf) {
    int i = blockIdx.x * 256 + threadIdx.x;
    if (i < 49152) {
        int n = i / 192, k = i % 192;
        Wct[i] = f2bf(Wc[k * 256 + n]);
    } else if (i < 114688) {
        int j = i - 49152;
        int n = j >> 8, k = j & 255;
        W1t[j] = f2bf(W1[k * 256 + n]);
    } else if (i < 131072) {
        int j = i - 114688;
        int n = j >> 8, k = j & 255;
        W2t[j] = f2bf(W2[k * 64 + n]);
    } else {
        int j = i - 131072;
        if (j < B_ * N_ * C_) xbf[j] = f2bf(x[j]);
    }
}

// bf16 gather propagation: O[b,n,c] = sum_j bf2f(T[b,ssrc[j],c]) * sw[j]
__global__ void k_prop(const u16* __restrict__ T, const int* __restrict__ offs,
                       const int* __restrict__ ssrc, const float* __restrict__ sw,
                       u16* __restrict__ O) {
    int g = blockIdx.x * 256 + threadIdx.x;
    int c = g & 63;
    int bn = g >> 6;
    int n = bn % N_;
    int b = g / (N_ * C_);
    const u16* Tb = T + (size_t)b * (N_ * C_);
    int s = offs[n], e = offs[n + 1];
    float sum = 0.f;
    int j = s;
    for (; j + 4 <= e; j += 4) {
        int i0 = ssrc[j], i1 = ssrc[j + 1], i2 = ssrc[j + 2], i3 = ssrc[j + 3];
        float w0 = sw[j], w1 = sw[j + 1], w2 = sw[j + 2], w3 = sw[j + 3];
        sum += bf2f(Tb[i0 * 64 + c]) * w0 + bf2f(Tb[i1 * 64 + c]) * w1
             + bf2f(Tb[i2 * 64 + c]) * w2 + bf2f(Tb[i3 * 64 + c]) * w3;
    }
    for (; j < e; ++j) sum += bf2f(Tb[ssrc[j] * 64 + c]) * sw[j];
    O[g] = f2bf(sum);
}

// ---- fused cheb-einsum + MLP, bf16 MFMA ----------------------------------
// 32 rows/block, 256 threads (4 waves). Padded LDS strides (200 / 264 u16)
// to avoid bank conflicts (row stride = 4 dwords mod 32 banks).
__global__ __launch_bounds__(256) void k_fused(
        const float* __restrict__ x, const u16* __restrict__ xbf,
        const u16* __restrict__ Tx1, const u16* __restrict__ P1,
        const u16* __restrict__ Wct, const float* __restrict__ bc,
        const u16* __restrict__ W1t, const float* __restrict__ b1,
        const u16* __restrict__ W2t, const float* __restrict__ b2,
        const float* __restrict__ beta, float* __restrict__ out) {
    __shared__ u16 buf0[32 * 264];  // A0 (stride 200), reused as A2 (stride 264)
    __shared__ u16 buf1[32 * 264];  // A1 (stride 264)
    int t = threadIdx.x;

    // stage A0 = [xbf | Tx1 | 2*P1 - x] bf16, row-major, K-stride 200
    {
        size_t base = (size_t)blockIdx.x * 512;  // uint2 (4-elem) units
        const uint2* xb = (const uint2*)xbf + base;
        const uint2* tb = (const uint2*)Tx1 + base;
        const uint2* pb = (const uint2*)P1 + base;
#pragma unroll
        for (int rep = 0; rep < 2; ++rep) {
            int p = t + rep * 256;
            int r = p >> 4, c4 = p & 15;
            uint2 xv = xb[p];
            uint2 tv = tb[p];
            uint2 pv = pb[p];
            uint2 t2;
            t2.x = pack2(2.f * bf2f(pv.x & 0xffff) - bf2f(xv.x & 0xffff),
                         2.f * bf2f(pv.x >> 16)    - bf2f(xv.x >> 16));
            t2.y = pack2(2.f * bf2f(pv.y & 0xffff) - bf2f(xv.y & 0xffff),
                         2.f * bf2f(pv.y >> 16)    - bf2f(xv.y >> 16));
            *(uint2*)&buf0[r * 200 + c4 * 4] = xv;
            *(uint2*)&buf0[r * 200 + 64 + c4 * 4] = tv;
            *(uint2*)&buf0[r * 200 + 128 + c4 * 4] = t2;
        }
    }
    __syncthreads();

    float sp = logf(1.f + expf(beta[0]));
    int lane = t & 63, w = t >> 6;
    int m = lane & 15, quad = lane >> 4;

    // ---- GEMM1: h = A0[32x192] @ Wc[192x256], +bc, swish -> buf1
    {
        f32x4 acc[2][4] = {};
        for (int kc = 0; kc < 6; ++kc) {
            int koff = kc * 32 + quad * 8;
            bf16x8 a0 = *(const bf16x8*)&buf0[m * 200 + koff];
            bf16x8 a1 = *(const bf16x8*)&buf0[(16 + m) * 200 + koff];
#pragma unroll
            for (int nt = 0; nt < 4; ++nt) {
                bf16x8 b = *(const bf16x8*)&Wct[(w * 64 + nt * 16 + m) * 192 + koff];
                acc[0][nt] = __builtin_amdgcn_mfma_f32_16x16x32_bf16(a0, b, acc[0][nt], 0, 0, 0);
                acc[1][nt] = __builtin_amdgcn_mfma_f32_16x16x32_bf16(a1, b, acc[1][nt], 0, 0, 0);
            }
        }
#pragma unroll
        for (int mt = 0; mt < 2; ++mt)
#pragma unroll
            for (int nt = 0; nt < 4; ++nt) {
                int col = w * 64 + nt * 16 + m;
                float bcv = bc[col];
#pragma unroll
                for (int i = 0; i < 4; ++i) {
                    int row = mt * 16 + quad * 4 + i;
                    buf1[row * 264 + col] = f2bf(swish_f(acc[mt][nt][i] + bcv, sp));
                }
            }
    }
    __syncthreads();

    // ---- GEMM2: h2 = A1[32x256] @ W1[256x256], +b1, swish -> buf0
    {
        f32x4 acc[2][4] = {};
        for (int kc = 0; kc < 8; ++kc) {
            int koff = kc * 32 + quad * 8;
            bf16x8 a0 = *(const bf16x8*)&buf1[m * 264 + koff];
            bf16x8 a1 = *(const bf16x8*)&buf1[(16 + m) * 264 + koff];
#pragma unroll
            for (int nt = 0; nt < 4; ++nt) {
                bf16x8 b = *(const bf16x8*)&W1t[(w * 64 + nt * 16 + m) * 256 + koff];
                acc[0][nt] = __builtin_amdgcn_mfma_f32_16x16x32_bf16(a0, b, acc[0][nt], 0, 0, 0);
                acc[1][nt] = __builtin_amdgcn_mfma_f32_16x16x32_bf16(a1, b, acc[1][nt], 0, 0, 0);
            }
        }
#pragma unroll
        for (int mt = 0; mt < 2; ++mt)
#pragma unroll
            for (int nt = 0; nt < 4; ++nt) {
                int col = w * 64 + nt * 16 + m;
                float b1v = b1[col];
#pragma unroll
                for (int i = 0; i < 4; ++i) {
                    int row = mt * 16 + quad * 4 + i;
                    buf0[row * 264 + col] = f2bf(swish_f(acc[mt][nt][i] + b1v, sp));
                }
            }
    }
    __syncthreads();

    // ---- GEMM3: Fx = A2[32x256] @ W2[256x64], +b2; out = Fx + x, Fx
    {
        f32x4 acc3[2] = {};
        for (int kc = 0; kc < 8; ++kc) {
            int koff = kc * 32 + quad * 8;
            bf16x8 a0 = *(const bf16x8*)&buf0[m * 264 + koff];
            bf16x8 a1 = *(const bf16x8*)&buf0[(16 + m) * 264 + koff];
            bf16x8 b = *(const bf16x8*)&W2t[(w * 16 + m) * 256 + koff];
            acc3[0] = __builtin_amdgcn_mfma_f32_16x16x32_bf16(a0, b, acc3[0], 0, 0, 0);
            acc3[1] = __builtin_amdgcn_mfma_f32_16x16x32_bf16(a1, b, acc3[1], 0, 0, 0);
        }
        int col = w * 16 + m;
        float b2v = b2[col];
#pragma unroll
        for (int mt = 0; mt < 2; ++mt)
#pragma unroll
            for (int i = 0; i < 4; ++i) {
                int row = mt * 16 + quad * 4 + i;
                size_t g = ((size_t)blockIdx.x * 32 + row) * 64 + col;
                float f = acc3[mt][i] + b2v;
                out[g] = f + x[g];
                out[OUT_OFF_ + g] = f;
            }
    }
}

extern "C" void kernel_launch(void* const* d_in, const int* in_sizes, int n_in,
                              void* d_out, int out_size, void* d_ws, size_t ws_size,
                              hipStream_t stream) {
    const float* x    = (const float*)d_in[0];
    const float* ew   = (const float*)d_in[1];
    const float* Wc   = (const float*)d_in[2];
    const float* bc   = (const float*)d_in[3];
    const float* W1   = (const float*)d_in[4];
    const float* b1   = (const float*)d_in[5];
    const float* W2   = (const float*)d_in[6];
    const float* b2   = (const float*)d_in[7];
    const float* beta = (const float*)d_in[8];
    const int*   ei   = (const int*)d_in[9];
    const int* src = ei;
    const int* dst = ei + E_;
    float* out = (float*)d_out;

    // workspace layout (float units)
    float* ws = (float*)d_ws;
    float* deg    = ws + 0;                 // N
    float* dis    = ws + 10000;             // N
    int*   cnt    = (int*)(ws + 20000);     // N
    int*   offs   = (int*)(ws + 30000);     // N+1 (pad to 10008)
    int*   cursor = (int*)(ws + 40008);     // N
    int*   ssrc   = (int*)(ws + 50008);     // E
    float* sw     = ws + 210008;            // E
    u16*   xbf    = (u16*)(ws + 370008);    // B*N*C u16 (2.56M floats)
    u16*   Tx1    = (u16*)(ws + 2930008);   // B*N*C u16
    u16*   P1     = (u16*)(ws + 5490008);   // B*N*C u16
    u16*   Wct    = (u16*)(ws + 8050008);   // 49152 u16
    u16*   W1t    = (u16*)(ws + 8074584);   // 65536 u16
    u16*   W2t    = (u16*)(ws + 8107352);   // 16384 u16
    // total ~8.12M floats (~32.5 MB)

    hipMemsetAsync(deg, 0, (size_t)N_ * sizeof(float), stream);
    hipMemsetAsync(cnt, 0, (size_t)N_ * sizeof(int), stream);

    k_deg<<<(E_ + 255) / 256, 256, 0, stream>>>(dst, ew, deg, cnt);
    k_dis<<<(N_ + 255) / 256, 256, 0, stream>>>(deg, dis);
    k_scan<<<1, 1024, 0, stream>>>(cnt, offs, cursor);
    k_scatter<<<(E_ + 255) / 256, 256, 0, stream>>>(src, dst, ew, dis, cursor, ssrc, sw);
    k_prepw<<<(131072 + B_ * N_ * C_ + 255) / 256, 256, 0, stream>>>(
        Wc, W1, W2, x, Wct, W1t, W2t, xbf);
    k_prop<<<(B_ * N_ * C_) / 256, 256, 0, stream>>>(xbf, offs, ssrc, sw, Tx1);
    k_prop<<<(B_ * N_ * C_) / 256, 256, 0, stream>>>(Tx1, offs, ssrc, sw, P1);
    k_fused<<<ROWS_ / 32, 256, 0, stream>>>(x, xbf, Tx1, P1, Wct, bc, W1t, b1,
                                            W2t, b2, beta, out);
}

// Round 4
// 262.456 us; speedup vs baseline: 2.7766x; 1.2218x over previous
//
#include <hip/hip_runtime.h>
#include <cstdint>
#include <cstddef>

#define B_ 8
#define N_ 10000
#define C_ 64
#define DIM_ 256
#define E_ 160000
#define ROWS_ (B_ * N_)            // 80000
#define OUT_OFF_ ((size_t)B_ * N_ * C_)  // 5,120,000

typedef unsigned short u16;
typedef unsigned int u32;
typedef __attribute__((ext_vector_type(8))) short bf16x8;
typedef __attribute__((ext_vector_type(4))) float f32x4;

__device__ __forceinline__ u16 f2bf(float f) {
    unsigned int u = __float_as_uint(f);
    unsigned int r = u + 0x7FFF + ((u >> 16) & 1);  // RNE
    return (u16)(r >> 16);
}
__device__ __forceinline__ float bf2f(u32 h) {      // low 16 bits hold bf16
    return __uint_as_float(h << 16);
}
__device__ __forceinline__ unsigned int pack2(float a, float b) {
    return (unsigned int)f2bf(a) | ((unsigned int)f2bf(b) << 16);
}
__device__ __forceinline__ float swish_f(float v, float sp) {
    float e = __expf(-v * sp);
    float s = __builtin_amdgcn_rcpf(1.0f + e);
    return v * s * (1.0f / 1.1f);
}

#define MFMA16(a, b, c) __builtin_amdgcn_mfma_f32_16x16x32_bf16(a, b, c, 0, 0, 0)

// ---- graph preprocessing -------------------------------------------------

__global__ void k_deg(const int* __restrict__ dst, const float* __restrict__ ew,
                      float* __restrict__ deg, int* __restrict__ cnt) {
    int e = blockIdx.x * 256 + threadIdx.x;
    if (e < E_) {
        int d = dst[e];
        atomicAdd(&deg[d], ew[e]);
        atomicAdd(&cnt[d], 1);
    }
}

__global__ void k_dis(const float* __restrict__ deg, float* __restrict__ dis) {
    int n = blockIdx.x * 256 + threadIdx.x;
    if (n < N_) {
        float d = deg[n];
        dis[n] = d > 0.f ? rsqrtf(d) : 0.f;
    }
}

__global__ void k_scan(const int* __restrict__ cnt, int* __restrict__ offs,
                       int* __restrict__ cursor) {
    __shared__ int part[1024];
    int t = threadIdx.x;
    const int CH = 10;
    int base = t * CH;
    int s = 0;
    for (int i = 0; i < CH; i++) {
        int idx = base + i;
        if (idx < N_) s += cnt[idx];
    }
    part[t] = s;
    __syncthreads();
    for (int off = 1; off < 1024; off <<= 1) {
        int v = 0;
        if (t >= off) v = part[t - off];
        __syncthreads();
        if (t >= off) part[t] += v;
        __syncthreads();
    }
    int run = (t > 0) ? part[t - 1] : 0;
    for (int i = 0; i < CH; i++) {
        int idx = base + i;
        if (idx < N_) {
            offs[idx] = run;
            cursor[idx] = run;
            run += cnt[idx];
        }
    }
    if (t == 1023) offs[N_] = run;
}

__global__ void k_scatter(const int* __restrict__ src, const int* __restrict__ dst,
                          const float* __restrict__ ew, const float* __restrict__ dis,
                          int* __restrict__ cursor, int* __restrict__ ssrc,
                          float* __restrict__ sw) {
    int e = blockIdx.x * 256 + threadIdx.x;
    if (e < E_) {
        int sn = src[e], dn = dst[e];
        float w = -(dis[sn] * ew[e] * dis[dn]);
        int p = atomicAdd(&cursor[dn], 1);
        ssrc[p] = sn;
        sw[p] = w;
    }
}

// weight transpose to N-major bf16 + vectorized x cast
__global__ void k_prepw(const float* __restrict__ Wc, const float* __restrict__ W1,
                        const float* __restrict__ W2, const float* __restrict__ x,
                        u16* __restrict__ Wct, u16* __restrict__ W1t,
                        u16* __restrict__ W2t, u16* __restrict__ xbf) {
    int i = blockIdx.x * 256 + threadIdx.x;
    if (i < 49152) {
        int nr = i / 192, k = i % 192;
        Wct[i] = f2bf(Wc[k * 256 + nr]);
    } else if (i < 114688) {
        int j = i - 49152;
        int nr = j >> 8, k = j & 255;
        W1t[j] = f2bf(W1[k * 256 + nr]);
    } else if (i < 131072) {
        int j = i - 114688;
        int nr = j >> 8, k = j & 255;
        W2t[j] = f2bf(W2[k * 64 + nr]);
    } else {
        int j = i - 131072;
        if (j < (B_ * N_ * C_) / 4) {
            float4 v = ((const float4*)x)[j];
            uint2 pv = {pack2(v.x, v.y), pack2(v.z, v.w)};
            ((uint2*)xbf)[j] = pv;
        }
    }
}

// bf16 gather SpMM. One wave per (batch, node); XCD-batch swizzle (b = blk&7).
// mode==1: O = 2*sum - xin  (fused Tx2 computation)
__global__ __launch_bounds__(256) void k_prop(
        const u16* __restrict__ T, const int* __restrict__ offs,
        const int* __restrict__ ssrc, const float* __restrict__ sw,
        const u16* __restrict__ xin, u16* __restrict__ O, int mode) {
    int w = __builtin_amdgcn_readfirstlane(threadIdx.x >> 6);
    int lane = threadIdx.x & 63;
    int b = blockIdx.x & 7;
    int nb = blockIdx.x >> 3;
    int n = nb * 4 + w;
    const u16* Tb = T + (size_t)b * (N_ * C_);
    int s = offs[n], e = offs[n + 1];
    float sum = 0.f;
    int j = s;
    for (; j < e && (j & 3); ++j) sum += bf2f(Tb[(size_t)ssrc[j] * 64 + lane]) * sw[j];
    for (; j + 4 <= e; j += 4) {
        int4 idx = *(const int4*)&ssrc[j];
        float4 wv = *(const float4*)&sw[j];
        sum += bf2f(Tb[(size_t)idx.x * 64 + lane]) * wv.x
             + bf2f(Tb[(size_t)idx.y * 64 + lane]) * wv.y
             + bf2f(Tb[(size_t)idx.z * 64 + lane]) * wv.z
             + bf2f(Tb[(size_t)idx.w * 64 + lane]) * wv.w;
    }
    for (; j < e; ++j) sum += bf2f(Tb[(size_t)ssrc[j] * 64 + lane]) * sw[j];
    size_t g = ((size_t)b * N_ + n) * 64 + lane;
    float v = sum;
    if (mode == 1) v = 2.f * sum - bf2f(xin[g]);
    O[g] = f2bf(v);
}

// ---- fused cheb-einsum + MLP, bf16 MFMA, M=64 rows/block -----------------
// 256 threads (4 waves); wave w owns a 64-col slice (16-col for GEMM3).
// B fragments double-buffered from L2; each B-load feeds 4 MFMAs.
__global__ __launch_bounds__(256) void k_fused(
        const float* __restrict__ x, const u16* __restrict__ xbf,
        const u16* __restrict__ Tx1, const u16* __restrict__ Tx2,
        const u16* __restrict__ Wct, const float* __restrict__ bc,
        const u16* __restrict__ W1t, const float* __restrict__ b1,
        const u16* __restrict__ W2t, const float* __restrict__ b2,
        const float* __restrict__ beta, float* __restrict__ out) {
    __shared__ u16 buf0[64 * 264];  // A0 (stride 200), later h2/A2 (stride 264)
    __shared__ u16 buf1[64 * 264];  // h/A1 (stride 264)
    int t = threadIdx.x;

    // stage A0 = [xbf | Tx1 | Tx2] bf16, row-major, K-stride 200
    {
        size_t base = (size_t)blockIdx.x * 1024;  // uint2 units (64 rows x 16)
        const uint2* xb = (const uint2*)xbf + base;
        const uint2* tb = (const uint2*)Tx1 + base;
        const uint2* pb = (const uint2*)Tx2 + base;
#pragma unroll
        for (int rep = 0; rep < 4; ++rep) {
            int p = t + rep * 256;
            int r = p >> 4, c4 = p & 15;
            *(uint2*)&buf0[r * 200 + c4 * 4] = xb[p];
            *(uint2*)&buf0[r * 200 + 64 + c4 * 4] = tb[p];
            *(uint2*)&buf0[r * 200 + 128 + c4 * 4] = pb[p];
        }
    }
    __syncthreads();

    float sp = logf(1.f + expf(beta[0]));
    int lane = t & 63, w = t >> 6;
    int m = lane & 15, quad = lane >> 4;

    // ---- GEMM1: h = A0[64x192] @ Wc[192x256], +bc, swish -> buf1
    {
        f32x4 acc[4][4] = {};
        bf16x8 bcur[4], bnxt[4];
        const u16* Wp = Wct + (w * 64 + m) * 192 + quad * 8;
#pragma unroll
        for (int nt = 0; nt < 4; ++nt) bcur[nt] = *(const bf16x8*)(Wp + nt * 16 * 192);
        for (int kc = 0; kc < 6; ++kc) {
            if (kc < 5) {
#pragma unroll
                for (int nt = 0; nt < 4; ++nt)
                    bnxt[nt] = *(const bf16x8*)(Wp + nt * 16 * 192 + (kc + 1) * 32);
            }
            int koff = kc * 32 + quad * 8;
            bf16x8 a0 = *(const bf16x8*)&buf0[m * 200 + koff];
            bf16x8 a1 = *(const bf16x8*)&buf0[(16 + m) * 200 + koff];
            bf16x8 a2 = *(const bf16x8*)&buf0[(32 + m) * 200 + koff];
            bf16x8 a3 = *(const bf16x8*)&buf0[(48 + m) * 200 + koff];
#pragma unroll
            for (int nt = 0; nt < 4; ++nt) {
                acc[0][nt] = MFMA16(a0, bcur[nt], acc[0][nt]);
                acc[1][nt] = MFMA16(a1, bcur[nt], acc[1][nt]);
                acc[2][nt] = MFMA16(a2, bcur[nt], acc[2][nt]);
                acc[3][nt] = MFMA16(a3, bcur[nt], acc[3][nt]);
            }
#pragma unroll
            for (int nt = 0; nt < 4; ++nt) bcur[nt] = bnxt[nt];
        }
#pragma unroll
        for (int mt = 0; mt < 4; ++mt)
#pragma unroll
            for (int nt = 0; nt < 4; ++nt) {
                int col = w * 64 + nt * 16 + m;
                float bcv = bc[col];
#pragma unroll
                for (int i = 0; i < 4; ++i) {
                    int row = mt * 16 + quad * 4 + i;
                    buf1[row * 264 + col] = f2bf(swish_f(acc[mt][nt][i] + bcv, sp));
                }
            }
    }
    __syncthreads();

    // ---- GEMM2: h2 = A1[64x256] @ W1[256x256], +b1, swish -> buf0
    {
        f32x4 acc[4][4] = {};
        bf16x8 bcur[4], bnxt[4];
        const u16* Wp = W1t + (w * 64 + m) * 256 + quad * 8;
#pragma unroll
        for (int nt = 0; nt < 4; ++nt) bcur[nt] = *(const bf16x8*)(Wp + nt * 16 * 256);
        for (int kc = 0; kc < 8; ++kc) {
            if (kc < 7) {
#pragma unroll
                for (int nt = 0; nt < 4; ++nt)
                    bnxt[nt] = *(const bf16x8*)(Wp + nt * 16 * 256 + (kc + 1) * 32);
            }
            int koff = kc * 32 + quad * 8;
            bf16x8 a0 = *(const bf16x8*)&buf1[m * 264 + koff];
            bf16x8 a1 = *(const bf16x8*)&buf1[(16 + m) * 264 + koff];
            bf16x8 a2 = *(const bf16x8*)&buf1[(32 + m) * 264 + koff];
            bf16x8 a3 = *(const bf16x8*)&buf1[(48 + m) * 264 + koff];
#pragma unroll
            for (int nt = 0; nt < 4; ++nt) {
                acc[0][nt] = MFMA16(a0, bcur[nt], acc[0][nt]);
                acc[1][nt] = MFMA16(a1, bcur[nt], acc[1][nt]);
                acc[2][nt] = MFMA16(a2, bcur[nt], acc[2][nt]);
                acc[3][nt] = MFMA16(a3, bcur[nt], acc[3][nt]);
            }
#pragma unroll
            for (int nt = 0; nt < 4; ++nt) bcur[nt] = bnxt[nt];
        }
        __syncthreads();  // all waves done reading buf0's A0? (A0 dead since GEMM1)
#pragma unroll
        for (int mt = 0; mt < 4; ++mt)
#pragma unroll
            for (int nt = 0; nt < 4; ++nt) {
                int col = w * 64 + nt * 16 + m;
                float b1v = b1[col];
#pragma unroll
                for (int i = 0; i < 4; ++i) {
                    int row = mt * 16 + quad * 4 + i;
                    buf0[row * 264 + col] = f2bf(swish_f(acc[mt][nt][i] + b1v, sp));
                }
            }
    }
    __syncthreads();

    // ---- GEMM3: Fx = A2[64x256] @ W2[256x64], +b2; out = Fx + x, Fx
    {
        f32x4 acc3[4] = {};
        bf16x8 bcur, bnxt;
        const u16* Wp = W2t + (w * 16 + m) * 256 + quad * 8;
        bcur = *(const bf16x8*)Wp;
        for (int kc = 0; kc < 8; ++kc) {
            if (kc < 7) bnxt = *(const bf16x8*)(Wp + (kc + 1) * 32);
            int koff = kc * 32 + quad * 8;
            bf16x8 a0 = *(const bf16x8*)&buf0[m * 264 + koff];
            bf16x8 a1 = *(const bf16x8*)&buf0[(16 + m) * 264 + koff];
            bf16x8 a2 = *(const bf16x8*)&buf0[(32 + m) * 264 + koff];
            bf16x8 a3 = *(const bf16x8*)&buf0[(48 + m) * 264 + koff];
            acc3[0] = MFMA16(a0, bcur, acc3[0]);
            acc3[1] = MFMA16(a1, bcur, acc3[1]);
            acc3[2] = MFMA16(a2, bcur, acc3[2]);
            acc3[3] = MFMA16(a3, bcur, acc3[3]);
            bcur = bnxt;
        }
        int col = w * 16 + m;
        float b2v = b2[col];
#pragma unroll
        for (int mt = 0; mt < 4; ++mt)
#pragma unroll
            for (int i = 0; i < 4; ++i) {
                int row = mt * 16 + quad * 4 + i;
                size_t g = ((size_t)blockIdx.x * 64 + row) * 64 + col;
                float f = acc3[mt][i] + b2v;
                out[g] = f + x[g];
                out[OUT_OFF_ + g] = f;
            }
    }
}

extern "C" void kernel_launch(void* const* d_in, const int* in_sizes, int n_in,
                              void* d_out, int out_size, void* d_ws, size_t ws_size,
                              hipStream_t stream) {
    const float* x    = (const float*)d_in[0];
    const float* ew   = (const float*)d_in[1];
    const float* Wc   = (const float*)d_in[2];
    const float* bc   = (const float*)d_in[3];
    const float* W1   = (const float*)d_in[4];
    const float* b1   = (const float*)d_in[5];
    const float* W2   = (const float*)d_in[6];
    const float* b2   = (const float*)d_in[7];
    const float* beta = (const float*)d_in[8];
    const int*   ei   = (const int*)d_in[9];
    const int* src = ei;
    const int* dst = ei + E_;
    float* out = (float*)d_out;

    // workspace layout (float units)
    float* ws = (float*)d_ws;
    float* deg    = ws + 0;                 // N
    float* dis    = ws + 10000;             // N
    int*   cnt    = (int*)(ws + 20000);     // N
    int*   offs   = (int*)(ws + 30000);     // N+1 (pad to 10008)
    int*   cursor = (int*)(ws + 40008);     // N
    int*   ssrc   = (int*)(ws + 50008);     // E
    float* sw     = ws + 210008;            // E
    u16*   xbf    = (u16*)(ws + 370008);    // B*N*C u16
    u16*   Tx1    = (u16*)(ws + 2930008);   // B*N*C u16
    u16*   Tx2    = (u16*)(ws + 5490008);   // B*N*C u16
    u16*   Wct    = (u16*)(ws + 8050008);   // 49152 u16
    u16*   W1t    = (u16*)(ws + 8074584);   // 65536 u16
    u16*   W2t    = (u16*)(ws + 8107352);   // 16384 u16

    hipMemsetAsync(deg, 0, (size_t)N_ * sizeof(float), stream);
    hipMemsetAsync(cnt, 0, (size_t)N_ * sizeof(int), stream);

    k_deg<<<(E_ + 255) / 256, 256, 0, stream>>>(dst, ew, deg, cnt);
    k_dis<<<(N_ + 255) / 256, 256, 0, stream>>>(deg, dis);
    k_scan<<<1, 1024, 0, stream>>>(cnt, offs, cursor);
    k_scatter<<<(E_ + 255) / 256, 256, 0, stream>>>(src, dst, ew, dis, cursor, ssrc, sw);
    k_prepw<<<(131072 + (B_ * N_ * C_) / 4 + 255) / 256, 256, 0, stream>>>(
        Wc, W1, W2, x, Wct, W1t, W2t, xbf);
    k_prop<<<N_ / 4 * 8, 256, 0, stream>>>(xbf, offs, ssrc, sw, xbf, Tx1, 0);
    k_prop<<<N_ / 4 * 8, 256, 0, stream>>>(Tx1, offs, ssrc, sw, xbf, Tx2, 1);
    k_fused<<<ROWS_ / 64, 256, 0, stream>>>(x, xbf, Tx1, Tx2, Wct, bc, W1t, b1,
                                            W2t, b2, beta, out);
}